// Round 8
// baseline (731.342 us; speedup 1.0000x reference)
//
#include <hip/hip_runtime.h>
#include <hip/hip_bf16.h>
#include <cstdint>
#include <cstddef>

// Problem constants
#define T_TOK 4096   // BATCH*SEQ
#define DM    1024   // D_MODEL
#define DF    4096   // D_FF
#define NE    8      // N_EXPERTS (TOP_K = 2)
#define MAXRB 104    // 128-row blocks: padded experts (<=72) + shared (32)
#define RBX   13     // row-blocks per XCD (104/8)

typedef unsigned short u16;
typedef __attribute__((ext_vector_type(8))) short  short8;
typedef __attribute__((ext_vector_type(8))) unsigned short u16x8;
typedef __attribute__((ext_vector_type(4))) float  f32x4;
typedef __attribute__((ext_vector_type(4))) unsigned short u16x4;

__device__ __forceinline__ u16 f2b(float f) {
  union { float f; uint32_t u; } v; v.f = f;
  uint32_t u = v.u;
  u += 0x7fffu + ((u >> 16) & 1u);   // round-to-nearest-even
  return (u16)(u >> 16);
}
__device__ __forceinline__ float b2f(u16 b) {
  union { uint32_t u; float f; } v; v.u = ((uint32_t)b) << 16; return v.f;
}

// async global->LDS, 16B per lane. LDS dest is WAVE-UNIFORM base; HW adds lane*16.
__device__ __forceinline__ void gload_lds16(const u16* gsrc, u16* lds) {
  __builtin_amdgcn_global_load_lds(
      (const __attribute__((address_space(1))) void*)gsrc,
      (__attribute__((address_space(3))) void*)lds, 16, 0, 0);
}

// ---------------- merged transpose+convert: all 18 weight slices, u16x8 writes -------
// id<9216: slice z of {W1 experts, Ws1}: fp32 [DM][DF] -> bf16 [DF][DM]
// id>=9216: slice z of {W2 experts, Ws2}: fp32 [DF][DM] -> bf16 [DM][DF]
__global__ void transpose_w(const float* __restrict__ W1, const float* __restrict__ Ws1,
                            const float* __restrict__ W2, const float* __restrict__ Ws2,
                            u16* __restrict__ W1T, u16* __restrict__ Ws1T,
                            u16* __restrict__ W2T, u16* __restrict__ Ws2T) {
  __shared__ float tile[64][65];
  const int id = blockIdx.x;
  const int half = (id >= 9216) ? 1 : 0;
  const int lid = id - half * 9216;
  const int z = lid >> 10, t = lid & 1023;
  const int R = half ? DF : DM;
  const int C = half ? DM : DF;
  const float* src; u16* dst;
  const size_t zoff = (size_t)z * DM * DF;
  if (half == 0) { if (z < NE) { src = W1 + zoff; dst = W1T + zoff; } else { src = Ws1; dst = Ws1T; } }
  else           { if (z < NE) { src = W2 + zoff; dst = W2T + zoff; } else { src = Ws2; dst = Ws2T; } }
  const int bx = half ? (t & 15) : (t & 63);
  const int by = half ? (t >> 4) : (t >> 6);
  const int c0 = bx * 64, r0 = by * 64;
  const int tid = threadIdx.x;                // 256
  const int tx = tid & 63, ty = tid >> 6;
  for (int i = ty; i < 64; i += 4)
    tile[i][tx] = src[(size_t)(r0 + i) * C + c0 + tx];
  __syncthreads();
  const int p = tid & 7, i0 = tid >> 3;       // 8 lanes x 16B = 128B contiguous per i
  for (int i = i0; i < 64; i += 32) {
    u16x8 v;
#pragma unroll
    for (int j = 0; j < 8; ++j) v[j] = f2b(tile[8 * p + j][i]);
    *reinterpret_cast<u16x8*>(&dst[(size_t)(c0 + i) * R + r0 + 8 * p]) = v;
  }
}

// ---------------- gating + x conversion fused: fp32 logits, top-2, write Xb ----------
// one wave per token (4/block); vectorized f32x4 x-reads; no atomics.
__global__ void gating_cvt(const float* __restrict__ x, const float* __restrict__ Wg,
                           u16* __restrict__ Xb, int* __restrict__ top_e,
                           float* __restrict__ top_w) {
  int t = (blockIdx.x * blockDim.x + threadIdx.x) >> 6;
  int lane = threadIdx.x & 63;
  if (t >= T_TOK) return;
  const float* xr = x + (size_t)t * DM;
  u16* xbr = Xb + (size_t)t * DM;
  float acc[NE];
#pragma unroll
  for (int e = 0; e < NE; ++e) acc[e] = 0.f;
#pragma unroll
  for (int it = 0; it < 4; ++it) {
    int d0 = it * 256 + lane * 4;
    f32x4 v = *reinterpret_cast<const f32x4*>(xr + d0);
    u16x4 o;
    o.x = f2b(v.x); o.y = f2b(v.y); o.z = f2b(v.z); o.w = f2b(v.w);
    *reinterpret_cast<u16x4*>(xbr + d0) = o;
#pragma unroll
    for (int j = 0; j < 4; ++j) {
      const float* wr = Wg + (size_t)(d0 + j) * NE;
      float xv = v[j];
#pragma unroll
      for (int e = 0; e < NE; ++e) acc[e] += xv * wr[e];
    }
  }
#pragma unroll
  for (int off = 32; off > 0; off >>= 1) {
#pragma unroll
    for (int e = 0; e < NE; ++e) acc[e] += __shfl_down(acc[e], off);
  }
  if (lane == 0) {
    int e0 = 0; float v0 = acc[0];
#pragma unroll
    for (int e = 1; e < NE; ++e) if (acc[e] > v0) { v0 = acc[e]; e0 = e; }
    int e1 = -1; float v1 = -3.4e38f;
#pragma unroll
    for (int e = 0; e < NE; ++e) if (e != e0 && acc[e] > v1) { v1 = acc[e]; e1 = e; }
    float s = expf(v1 - v0);              // v1 <= v0, stable
    float inv = 1.f / (1.f + s);
    top_e[t * 2] = e0; top_e[t * 2 + 1] = e1;
    top_w[t * 2] = inv; top_w[t * 2 + 1] = s * inv;
  }
}

// ---------------- deterministic slot assignment: 1 block, LDS prefix scan -----------
// slot of pair p = pad_off[e] + rank of p among pairs with expert e (p-order).
// No global atomics; fully deterministic.
__global__ void slots_kernel(const int* __restrict__ top_e, int* __restrict__ pad_off,
                             int* __restrict__ slot_of) {
  __shared__ int cnt[256][NE];    // 8 KB
  __shared__ int pos[NE + 2];
  const int tid = threadIdx.x;
  const int p0 = tid * 32;        // 256 threads x 32 pairs = 8192
#pragma unroll
  for (int e = 0; e < NE; ++e) cnt[tid][e] = 0;
#pragma unroll 1
  for (int i = 0; i < 32; ++i) cnt[tid][top_e[p0 + i]]++;
  __syncthreads();
  if (tid < NE) {                 // exclusive scan over threads, per expert
    int s = 0;
    for (int i = 0; i < 256; ++i) { int c = cnt[i][tid]; cnt[i][tid] = s; s += c; }
    pos[tid] = s;                 // total count for expert tid
  }
  __syncthreads();
  if (tid == 0) {
    int s = 0;
    for (int e = 0; e < NE; ++e) { int c = pos[e]; pos[e] = s; s += (c + 127) & ~127; }
    pos[NE] = s;                  // shared-expert base row
    pos[NE + 1] = s + T_TOK;      // total padded rows
  }
  __syncthreads();
#pragma unroll
  for (int e = 0; e < NE; ++e) cnt[tid][e] += pos[e];   // absolute running slot
#pragma unroll 1
  for (int i = 0; i < 32; ++i) {
    int e = top_e[p0 + i];
    slot_of[p0 + i] = cnt[tid][e]++;
  }
  if (tid < NE + 2) pad_off[tid] = pos[tid];
}

// ---------------- gather: copy Xb row to its slot in padded grouped Xg ----------------
// Padded slots keep stale garbage: feed only padded H/Ytmp rows, never read back.
__global__ void gather_x(const u16* __restrict__ Xb, const int* __restrict__ slot_of,
                         u16* __restrict__ Xg) {
  int p = blockIdx.x;                 // 0..2*T_TOK-1 ; token = p>>1
  int slot = slot_of[p];
  u16x8 v = reinterpret_cast<const u16x8*>(Xb + (size_t)(p >> 1) * DM)[threadIdx.x];
  reinterpret_cast<u16x8*>(Xg + (size_t)slot * DM)[threadIdx.x] = v;
}

// ---------------- grouped FFN GEMM: m97 structure, 128x128 tile, 4 waves -------------
// Dense padded row-space; 32KB LDS -> 5 blocks/CU; TLP hides load latency (m114).
// PASS 1: H[row] = relu(A[row] @ W1T^T + b1)   A = Xg (experts) / Xb (shared), K=1024
// PASS 2: Ytmp[ks][row] = H[row] @ W2T[ks]^T   K=4096 split 2x2048; bias+gate in combine
// L2-blocked swizzle: rbs partitioned across XCDs (13 each), rb INNERMOST within an
// XCD chunk -> per-XCD A-set (13 x 256KB = 3.3MB) stays L2-resident; each B panel
// gets 13x L2 reuse. (r7's rb-global-innermost thrashed A: FETCH 443MB vs 100 ideal.)
// LDS linear (gload_lds); conflicts killed by chunk-XOR on BOTH source and ds_read.
template <int PASS>
__global__ __launch_bounds__(256, 5)
void ffn_gemm(const u16* __restrict__ Xb, const u16* __restrict__ Xg,
              u16* __restrict__ H,
              const u16* __restrict__ WT, const u16* __restrict__ WsT,
              const float* __restrict__ bias_e, const float* __restrict__ bias_s,
              const int* __restrict__ pad_off, u16* __restrict__ Ytmp) {
  constexpr int K      = (PASS == 1) ? DM : DF;
  constexpr int N      = (PASS == 1) ? DF : DM;
  constexpr int NCOL   = N / 128;
  constexpr int KSPLIT = (PASS == 1) ? 1 : 2;
  constexpr int KLEN   = K / KSPLIT;
  constexpr size_t YHALF = (size_t)MAXRB * 128 * DM;

  // XCD-partitioned, L2-blocked ordering (assumes blockIdx round-robins XCDs mod 8)
  const int xcd = blockIdx.x & 7;
  const int c   = blockIdx.x >> 3;        // [0, NWG/8)
  const int rb  = xcd * RBX + c % RBX;    // rb innermost: A-set L2-resident per XCD
  const int cq  = c / RBX;
  int colb, ks;
  if (PASS == 1) { colb = cq; ks = 0; }
  else           { ks = cq >> 3; colb = cq & 7; }
  const int col0 = colb * 128;
  const int kbase = ks * KLEN;

  const int shbase = pad_off[NE];
  const int mtot   = pad_off[NE + 1];
  const int grow0  = rb * 128;            // global padded row (tile never spans experts)
  if (grow0 >= mtot) return;

  int e = NE;                             // shared unless below shbase
  if (grow0 < shbase) {
    e = 0;
#pragma unroll
    for (int i = 1; i < NE; ++i) if (grow0 >= pad_off[i]) e = i;
  }

  const u16* Ap;
  if (PASS == 1) Ap = (e < NE) ? (Xg + (size_t)grow0 * DM)
                               : (Xb + (size_t)(grow0 - shbase) * DM);
  else           Ap = H + (size_t)grow0 * DF;
  const u16* Bp = (e < NE) ? (WT + (size_t)e * (size_t)K * N) : WsT;   // [N][K]
  const float* bias = (e < NE) ? (bias_e + (size_t)e * N) : bias_s;

  __shared__ alignas(16) u16 As[128 * 64];
  __shared__ alignas(16) u16 Bs[128 * 64];

  const int tid = threadIdx.x;
  const int wv = tid >> 6, lane = tid & 63;
  // staging: call j covers rows j*32 + (wv*8 + lane>>3); 16B chunk = lane&7 (XOR-swz)
  const int srow = wv * 8 + (lane >> 3);
  const int schk = lane & 7;
  const u16* a_ptr[4];
  const u16* b_ptr[4];
#pragma unroll
  for (int j = 0; j < 4; ++j) {
    int r = j * 32 + srow;
    int cs = (schk ^ (r & 7)) * 8;        // pre-swizzled global column (elems)
    a_ptr[j] = Ap + (size_t)r * K + kbase + cs;
    b_ptr[j] = Bp + (size_t)(col0 + r) * K + kbase + cs;
  }
  const int ldso = wv * 512;              // wave-uniform LDS elem offset per 4KB call

  const int wr = wv >> 1, wc = wv & 1;    // 2x2 wave grid; per-wave output 64x64
  const int q = lane >> 4, r16 = lane & 15, r7 = r16 & 7;
  const int xk0 = (q ^ r7) * 8;           // kk=0: logical chunk q   -> phys
  const int xk1 = ((4 + q) ^ r7) * 8;     // kk=1: logical chunk 4+q -> phys

  f32x4 acc[4][4];
#pragma unroll
  for (int i = 0; i < 4; ++i)
#pragma unroll
    for (int j = 0; j < 4; ++j) acc[i][j] = (f32x4)0.f;

#pragma unroll 1
  for (int k0 = 0; k0 < KLEN; k0 += 64) {
    __syncthreads();                      // prev iter's LDS reads done
#pragma unroll
    for (int j = 0; j < 4; ++j) gload_lds16(a_ptr[j] + k0, As + j * 2048 + ldso);
#pragma unroll
    for (int j = 0; j < 4; ++j) gload_lds16(b_ptr[j] + k0, Bs + j * 2048 + ldso);
    __syncthreads();                      // vmcnt(0) drain at barrier: tile ready
#pragma unroll
    for (int kk = 0; kk < 2; ++kk) {
      const int xk = kk ? xk1 : xk0;
      short8 af[4], bf[4];
#pragma unroll
      for (int mt = 0; mt < 4; ++mt)
        af[mt] = *reinterpret_cast<const short8*>(&As[(wr * 64 + mt * 16 + r16) * 64 + xk]);
#pragma unroll
      for (int nt = 0; nt < 4; ++nt)
        bf[nt] = *reinterpret_cast<const short8*>(&Bs[(wc * 64 + nt * 16 + r16) * 64 + xk]);
#pragma unroll
      for (int mt = 0; mt < 4; ++mt)
#pragma unroll
        for (int nt = 0; nt < 4; ++nt)
          acc[mt][nt] = __builtin_amdgcn_mfma_f32_16x16x32_bf16(af[mt], bf[nt], acc[mt][nt], 0, 0, 0);
    }
  }

  // epilogue: C/D layout col=lane&15, row=(lane>>4)*4+reg  [verified m89/m91]
  u16* Yt = Ytmp + (size_t)ks * YHALF;
#pragma unroll
  for (int mt = 0; mt < 4; ++mt) {
    int rl = wr * 64 + mt * 16 + q * 4;
#pragma unroll
    for (int nt = 0; nt < 4; ++nt) {
      int col = col0 + wc * 64 + nt * 16 + r16;
      float bcol = (PASS == 1) ? bias[col] : 0.f;
#pragma unroll
      for (int v = 0; v < 4; ++v) {
        int r = rl + v;
        float val = acc[mt][nt][v] + bcol;
        if (PASS == 1) {
          val = fmaxf(val, 0.f);
          H[(size_t)(grow0 + r) * DF + col] = f2b(val);
        } else {
          Yt[(size_t)(grow0 + r) * DM + col] = f2b(val);
        }
      }
    }
  }
}

// ---------------- combine: out[t] = w0*(Y[s0]+b2[e0]) + w1*(Y[s1]+b2[e1]) + Y[sh]+bs2 ----
// Y[s] = Ya[s] + Yb[s] (split-K halves)
__global__ void combine_kernel(const u16* __restrict__ Ytmp, const int* __restrict__ slot_of,
                               const int* __restrict__ top_e, const float* __restrict__ top_w,
                               const float* __restrict__ b2, const float* __restrict__ bs2,
                               const int* __restrict__ pad_off, float* __restrict__ out) {
  constexpr size_t YHALF = (size_t)MAXRB * 128 * DM;
  int gid = blockIdx.x * blockDim.x + threadIdx.x;   // one per (token, 8-col group)
  int t = gid >> 7;
  int c8 = (gid & 127) * 8;
  if (t >= T_TOK) return;
  int shbase = pad_off[NE];
  int s0 = slot_of[t * 2], s1 = slot_of[t * 2 + 1];
  int e0 = top_e[t * 2],  e1 = top_e[t * 2 + 1];
  float w0 = top_w[t * 2], w1 = top_w[t * 2 + 1];
  u16x8 y0a = *reinterpret_cast<const u16x8*>(Ytmp + (size_t)s0 * DM + c8);
  u16x8 y0b = *reinterpret_cast<const u16x8*>(Ytmp + YHALF + (size_t)s0 * DM + c8);
  u16x8 y1a = *reinterpret_cast<const u16x8*>(Ytmp + (size_t)s1 * DM + c8);
  u16x8 y1b = *reinterpret_cast<const u16x8*>(Ytmp + YHALF + (size_t)s1 * DM + c8);
  u16x8 ysa = *reinterpret_cast<const u16x8*>(Ytmp + (size_t)(shbase + t) * DM + c8);
  u16x8 ysb = *reinterpret_cast<const u16x8*>(Ytmp + YHALF + (size_t)(shbase + t) * DM + c8);
  const float* b0 = b2 + (size_t)e0 * DM + c8;
  const float* b1p = b2 + (size_t)e1 * DM + c8;
  const float* bs = bs2 + c8;
  float r[8];
#pragma unroll
  for (int v = 0; v < 8; ++v)
    r[v] = w0 * (b2f(y0a[v]) + b2f(y0b[v]) + b0[v])
         + w1 * (b2f(y1a[v]) + b2f(y1b[v]) + b1p[v])
         + (b2f(ysa[v]) + b2f(ysb[v]) + bs[v]);
  float* o = out + (size_t)t * DM + c8;
#pragma unroll
  for (int v = 0; v < 8; ++v) o[v] = r[v];
}

extern "C" void kernel_launch(void* const* d_in, const int* in_sizes, int n_in,
                              void* d_out, int out_size, void* d_ws, size_t ws_size,
                              hipStream_t stream) {
  const float* x   = (const float*)d_in[0];
  const float* Wg  = (const float*)d_in[1];
  const float* W1  = (const float*)d_in[2];
  const float* b1  = (const float*)d_in[3];
  const float* W2  = (const float*)d_in[4];
  const float* b2  = (const float*)d_in[5];
  const float* Ws1 = (const float*)d_in[6];
  const float* bs1 = (const float*)d_in[7];
  const float* Ws2 = (const float*)d_in[8];
  const float* bs2 = (const float*)d_in[9];

  // workspace layout (~276 MiB)
  char* ws = (char*)d_ws;
  size_t off = 0;
  auto alloc = [&](size_t bytes) -> char* {
    char* p = ws + off;
    off = (off + bytes + 255) & ~(size_t)255;
    return p;
  };
  int*   pad_off = (int*)  alloc((NE + 2) * 4);
  int*   top_e   = (int*)  alloc((size_t)T_TOK * 2 * 4);
  float* top_w   = (float*)alloc((size_t)T_TOK * 2 * 4);
  int*   slot_of = (int*)  alloc((size_t)T_TOK * 2 * 4);
  u16*   Xb   = (u16*)alloc((size_t)T_TOK * DM * 2);         // 8 MB
  u16*   Xg   = (u16*)alloc((size_t)9216 * DM * 2);          // padded expert rows, 19 MB
  u16*   W1T  = (u16*)alloc((size_t)NE * DM * DF * 2);       // [e][DF][DM], 64 MB; dead after pass1
  u16*   W2T  = (u16*)alloc((size_t)NE * DM * DF * 2);       // [e][DM][DF], 64 MB
  u16*   Ws1T = (u16*)alloc((size_t)DM * DF * 2);            // [DF][DM], 8 MB
  u16*   Ws2T = (u16*)alloc((size_t)DM * DF * 2);            // [DM][DF], 8 MB
  u16*   H    = (u16*)alloc((size_t)MAXRB * 128 * DF * 2);   // 13312 rows, 104 MB
  u16*   Ytmp = W1T;   // 52 MB overlay (2 split-K halves): W1T rewritten every launch
  (void)ws_size; (void)in_sizes; (void)n_in;

  transpose_w<<<2 * 9 * 1024, 256, 0, stream>>>(W1, Ws1, W2, Ws2, W1T, Ws1T, W2T, Ws2T);
  gating_cvt<<<T_TOK / 4, 256, 0, stream>>>(x, Wg, Xb, top_e, top_w);
  slots_kernel<<<1, 256, 0, stream>>>(top_e, pad_off, slot_of);
  gather_x<<<2 * T_TOK, 128, 0, stream>>>(Xb, slot_of, Xg);

  // pass1: 32 colb x 104 rb = 3328 blocks, L2-blocked per XCD
  ffn_gemm<1><<<(DF / 128) * MAXRB, 256, 0, stream>>>(
      Xb, Xg, H, W1T, Ws1T, b1, bs1, pad_off, Ytmp);
  // pass2: 8 colb x 104 rb x 2 ks = 1664 blocks
  ffn_gemm<2><<<(DM / 128) * MAXRB * 2, 256, 0, stream>>>(
      Xb, Xg, H, W2T, Ws2T, b2, bs2, pad_off, Ytmp);

  combine_kernel<<<(T_TOK * 128) / 256, 256, 0, stream>>>(
      Ytmp, slot_of, top_e, top_w, b2, bs2, pad_off, (float*)d_out);
}

// Round 9
// 385.795 us; speedup vs baseline: 1.8957x; 1.8957x over previous
//
#include <hip/hip_runtime.h>
#include <hip/hip_bf16.h>
#include <cstdint>
#include <cstddef>

// Problem constants
#define T_TOK 4096   // BATCH*SEQ
#define DM    1024   // D_MODEL
#define DF    4096   // D_FF
#define NE    8      // N_EXPERTS (TOP_K = 2)
#define MAXRB 104    // 128-row blocks: padded experts (<=72) + shared (32)
#define RBX   13     // row-blocks per XCD (104/8)

typedef unsigned short u16;
typedef __attribute__((ext_vector_type(8))) short  short8;
typedef __attribute__((ext_vector_type(8))) unsigned short u16x8;
typedef __attribute__((ext_vector_type(4))) float  f32x4;
typedef __attribute__((ext_vector_type(4))) unsigned short u16x4;

__device__ __forceinline__ u16 f2b(float f) {
  union { float f; uint32_t u; } v; v.f = f;
  uint32_t u = v.u;
  u += 0x7fffu + ((u >> 16) & 1u);   // round-to-nearest-even
  return (u16)(u >> 16);
}
__device__ __forceinline__ float b2f(u16 b) {
  union { uint32_t u; float f; } v; v.u = ((uint32_t)b) << 16; return v.f;
}

// async global->LDS, 16B per lane. LDS dest is WAVE-UNIFORM base; HW adds lane*16.
__device__ __forceinline__ void gload_lds16(const u16* gsrc, u16* lds) {
  __builtin_amdgcn_global_load_lds(
      (const __attribute__((address_space(1))) void*)gsrc,
      (__attribute__((address_space(3))) void*)lds, 16, 0, 0);
}

// ---------------- merged transpose+convert: all 18 weight slices, u16x8 writes -------
__global__ void transpose_w(const float* __restrict__ W1, const float* __restrict__ Ws1,
                            const float* __restrict__ W2, const float* __restrict__ Ws2,
                            u16* __restrict__ W1T, u16* __restrict__ Ws1T,
                            u16* __restrict__ W2T, u16* __restrict__ Ws2T) {
  __shared__ float tile[64][65];
  const int id = blockIdx.x;
  const int half = (id >= 9216) ? 1 : 0;
  const int lid = id - half * 9216;
  const int z = lid >> 10, t = lid & 1023;
  const int R = half ? DF : DM;
  const int C = half ? DM : DF;
  const float* src; u16* dst;
  const size_t zoff = (size_t)z * DM * DF;
  if (half == 0) { if (z < NE) { src = W1 + zoff; dst = W1T + zoff; } else { src = Ws1; dst = Ws1T; } }
  else           { if (z < NE) { src = W2 + zoff; dst = W2T + zoff; } else { src = Ws2; dst = Ws2T; } }
  const int bx = half ? (t & 15) : (t & 63);
  const int by = half ? (t >> 4) : (t >> 6);
  const int c0 = bx * 64, r0 = by * 64;
  const int tid = threadIdx.x;                // 256
  const int tx = tid & 63, ty = tid >> 6;
  for (int i = ty; i < 64; i += 4)
    tile[i][tx] = src[(size_t)(r0 + i) * C + c0 + tx];
  __syncthreads();
  const int p = tid & 7, i0 = tid >> 3;       // 8 lanes x 16B = 128B contiguous per i
  for (int i = i0; i < 64; i += 32) {
    u16x8 v;
#pragma unroll
    for (int j = 0; j < 8; ++j) v[j] = f2b(tile[8 * p + j][i]);
    *reinterpret_cast<u16x8*>(&dst[(size_t)(c0 + i) * R + r0 + 8 * p]) = v;
  }
}

// ---------------- gating + x conversion fused: fp32 logits, top-2, write Xb ----------
__global__ void gating_cvt(const float* __restrict__ x, const float* __restrict__ Wg,
                           u16* __restrict__ Xb, int* __restrict__ top_e,
                           float* __restrict__ top_w) {
  int t = (blockIdx.x * blockDim.x + threadIdx.x) >> 6;
  int lane = threadIdx.x & 63;
  if (t >= T_TOK) return;
  const float* xr = x + (size_t)t * DM;
  u16* xbr = Xb + (size_t)t * DM;
  float acc[NE];
#pragma unroll
  for (int e = 0; e < NE; ++e) acc[e] = 0.f;
#pragma unroll
  for (int it = 0; it < 4; ++it) {
    int d0 = it * 256 + lane * 4;
    f32x4 v = *reinterpret_cast<const f32x4*>(xr + d0);
    u16x4 o;
    o.x = f2b(v.x); o.y = f2b(v.y); o.z = f2b(v.z); o.w = f2b(v.w);
    *reinterpret_cast<u16x4*>(xbr + d0) = o;
#pragma unroll
    for (int j = 0; j < 4; ++j) {
      const float* wr = Wg + (size_t)(d0 + j) * NE;
      float xv = v[j];
#pragma unroll
      for (int e = 0; e < NE; ++e) acc[e] += xv * wr[e];
    }
  }
#pragma unroll
  for (int off = 32; off > 0; off >>= 1) {
#pragma unroll
    for (int e = 0; e < NE; ++e) acc[e] += __shfl_down(acc[e], off);
  }
  if (lane == 0) {
    int e0 = 0; float v0 = acc[0];
#pragma unroll
    for (int e = 1; e < NE; ++e) if (acc[e] > v0) { v0 = acc[e]; e0 = e; }
    int e1 = -1; float v1 = -3.4e38f;
#pragma unroll
    for (int e = 0; e < NE; ++e) if (e != e0 && acc[e] > v1) { v1 = acc[e]; e1 = e; }
    float s = expf(v1 - v0);              // v1 <= v0, stable
    float inv = 1.f / (1.f + s);
    top_e[t * 2] = e0; top_e[t * 2 + 1] = e1;
    top_w[t * 2] = inv; top_w[t * 2 + 1] = s * inv;
  }
}

// ---------------- deterministic slot assignment: 1 block, LDS prefix scan -----------
__global__ void slots_kernel(const int* __restrict__ top_e, int* __restrict__ pad_off,
                             int* __restrict__ slot_of) {
  __shared__ int cnt[256][NE];    // 8 KB
  __shared__ int pos[NE + 2];
  const int tid = threadIdx.x;
  const int p0 = tid * 32;        // 256 threads x 32 pairs = 8192
#pragma unroll
  for (int e = 0; e < NE; ++e) cnt[tid][e] = 0;
#pragma unroll 1
  for (int i = 0; i < 32; ++i) cnt[tid][top_e[p0 + i]]++;
  __syncthreads();
  if (tid < NE) {                 // exclusive scan over threads, per expert
    int s = 0;
    for (int i = 0; i < 256; ++i) { int c = cnt[i][tid]; cnt[i][tid] = s; s += c; }
    pos[tid] = s;                 // total count for expert tid
  }
  __syncthreads();
  if (tid == 0) {
    int s = 0;
    for (int e = 0; e < NE; ++e) { int c = pos[e]; pos[e] = s; s += (c + 127) & ~127; }
    pos[NE] = s;                  // shared-expert base row
    pos[NE + 1] = s + T_TOK;      // total padded rows
  }
  __syncthreads();
#pragma unroll
  for (int e = 0; e < NE; ++e) cnt[tid][e] += pos[e];   // absolute running slot
#pragma unroll 1
  for (int i = 0; i < 32; ++i) {
    int e = top_e[p0 + i];
    slot_of[p0 + i] = cnt[tid][e]++;
  }
  if (tid < NE + 2) pad_off[tid] = pos[tid];
}

// ---------------- gather: copy Xb row to its slot in padded grouped Xg ----------------
__global__ void gather_x(const u16* __restrict__ Xb, const int* __restrict__ slot_of,
                         u16* __restrict__ Xg) {
  int p = blockIdx.x;                 // 0..2*T_TOK-1 ; token = p>>1
  int slot = slot_of[p];
  u16x8 v = reinterpret_cast<const u16x8*>(Xb + (size_t)(p >> 1) * DM)[threadIdx.x];
  reinterpret_cast<u16x8*>(Xg + (size_t)slot * DM)[threadIdx.x] = v;
}

// ---------------- grouped FFN GEMM: m97 structure, 128x128 tile, 4 waves -------------
// Dense padded row-space; 32KB LDS; __launch_bounds__(256,4): 64 VGPR + 64 acc-AGPR
// = 128 regs/wave fits EXACTLY at 4 waves/EU. (256,5) caps at ~102 -> acc spills to
// scratch (r8: WRITE 698MB, 2.3x slowdown). Registers, not LDS, bind occupancy here.
// PASS 1: H[row] = relu(A[row] @ W1T^T + b1)   A = Xg (experts) / Xb (shared), K=1024
// PASS 2: Ytmp[ks][row] = H[row] @ W2T[ks]^T   K=4096 split 2x2048; bias+gate in combine
// L2-blocked swizzle: rbs partitioned across XCDs (13 each), rb innermost per XCD ->
// per-XCD A-set (3.3MB) L2-resident, 13x B-panel reuse.
// LDS linear (gload_lds); conflicts killed by chunk-XOR on BOTH source and ds_read.
template <int PASS>
__global__ __launch_bounds__(256, 4)
void ffn_gemm(const u16* __restrict__ Xb, const u16* __restrict__ Xg,
              u16* __restrict__ H,
              const u16* __restrict__ WT, const u16* __restrict__ WsT,
              const float* __restrict__ bias_e, const float* __restrict__ bias_s,
              const int* __restrict__ pad_off, u16* __restrict__ Ytmp) {
  constexpr int K      = (PASS == 1) ? DM : DF;
  constexpr int N      = (PASS == 1) ? DF : DM;
  constexpr int KSPLIT = (PASS == 1) ? 1 : 2;
  constexpr int KLEN   = K / KSPLIT;
  constexpr size_t YHALF = (size_t)MAXRB * 128 * DM;

  // XCD-partitioned, L2-blocked ordering (blockIdx round-robins XCDs mod 8)
  const int xcd = blockIdx.x & 7;
  const int c   = blockIdx.x >> 3;        // [0, NWG/8)
  const int rb  = xcd * RBX + c % RBX;    // rb innermost: A-set L2-resident per XCD
  const int cq  = c / RBX;
  int colb, ks;
  if (PASS == 1) { colb = cq; ks = 0; }
  else           { ks = cq >> 3; colb = cq & 7; }
  const int col0 = colb * 128;
  const int kbase = ks * KLEN;

  const int shbase = pad_off[NE];
  const int mtot   = pad_off[NE + 1];
  const int grow0  = rb * 128;            // global padded row (tile never spans experts)
  if (grow0 >= mtot) return;

  int e = NE;                             // shared unless below shbase
  if (grow0 < shbase) {
    e = 0;
#pragma unroll
    for (int i = 1; i < NE; ++i) if (grow0 >= pad_off[i]) e = i;
  }

  const u16* Ap;
  if (PASS == 1) Ap = (e < NE) ? (Xg + (size_t)grow0 * DM)
                               : (Xb + (size_t)(grow0 - shbase) * DM);
  else           Ap = H + (size_t)grow0 * DF;
  const u16* Bp = (e < NE) ? (WT + (size_t)e * (size_t)K * N) : WsT;   // [N][K]
  const float* bias = (e < NE) ? (bias_e + (size_t)e * N) : bias_s;

  __shared__ alignas(16) u16 As[128 * 64];
  __shared__ alignas(16) u16 Bs[128 * 64];

  const int tid = threadIdx.x;
  const int wv = tid >> 6, lane = tid & 63;
  // staging: call j covers rows j*32 + (wv*8 + lane>>3); 16B chunk = lane&7 (XOR-swz)
  const int srow = wv * 8 + (lane >> 3);
  const int schk = lane & 7;
  const u16* a_ptr[4];
  const u16* b_ptr[4];
#pragma unroll
  for (int j = 0; j < 4; ++j) {
    int r = j * 32 + srow;
    int cs = (schk ^ (r & 7)) * 8;        // pre-swizzled global column (elems)
    a_ptr[j] = Ap + (size_t)r * K + kbase + cs;
    b_ptr[j] = Bp + (size_t)(col0 + r) * K + kbase + cs;
  }
  const int ldso = wv * 512;              // wave-uniform LDS elem offset per 4KB call

  const int wr = wv >> 1, wc = wv & 1;    // 2x2 wave grid; per-wave output 64x64
  const int q = lane >> 4, r16 = lane & 15, r7 = r16 & 7;
  const int xk0 = (q ^ r7) * 8;           // kk=0: logical chunk q   -> phys
  const int xk1 = ((4 + q) ^ r7) * 8;     // kk=1: logical chunk 4+q -> phys

  f32x4 acc[4][4];
#pragma unroll
  for (int i = 0; i < 4; ++i)
#pragma unroll
    for (int j = 0; j < 4; ++j) acc[i][j] = (f32x4)0.f;

#pragma unroll 1
  for (int k0 = 0; k0 < KLEN; k0 += 64) {
    __syncthreads();                      // prev iter's LDS reads done
#pragma unroll
    for (int j = 0; j < 4; ++j) gload_lds16(a_ptr[j] + k0, As + j * 2048 + ldso);
#pragma unroll
    for (int j = 0; j < 4; ++j) gload_lds16(b_ptr[j] + k0, Bs + j * 2048 + ldso);
    __syncthreads();                      // vmcnt(0) drain at barrier: tile ready
#pragma unroll
    for (int kk = 0; kk < 2; ++kk) {
      const int xk = kk ? xk1 : xk0;
      short8 af[4], bf[4];
#pragma unroll
      for (int mt = 0; mt < 4; ++mt)
        af[mt] = *reinterpret_cast<const short8*>(&As[(wr * 64 + mt * 16 + r16) * 64 + xk]);
#pragma unroll
      for (int nt = 0; nt < 4; ++nt)
        bf[nt] = *reinterpret_cast<const short8*>(&Bs[(wc * 64 + nt * 16 + r16) * 64 + xk]);
#pragma unroll
      for (int mt = 0; mt < 4; ++mt)
#pragma unroll
        for (int nt = 0; nt < 4; ++nt)
          acc[mt][nt] = __builtin_amdgcn_mfma_f32_16x16x32_bf16(af[mt], bf[nt], acc[mt][nt], 0, 0, 0);
    }
  }

  // epilogue: C/D layout col=lane&15, row=(lane>>4)*4+reg  [verified m89/m91]
  u16* Yt = Ytmp + (size_t)ks * YHALF;
#pragma unroll
  for (int mt = 0; mt < 4; ++mt) {
    int rl = wr * 64 + mt * 16 + q * 4;
#pragma unroll
    for (int nt = 0; nt < 4; ++nt) {
      int col = col0 + wc * 64 + nt * 16 + r16;
      float bcol = (PASS == 1) ? bias[col] : 0.f;
#pragma unroll
      for (int v = 0; v < 4; ++v) {
        int r = rl + v;
        float val = acc[mt][nt][v] + bcol;
        if (PASS == 1) {
          val = fmaxf(val, 0.f);
          H[(size_t)(grow0 + r) * DF + col] = f2b(val);
        } else {
          Yt[(size_t)(grow0 + r) * DM + col] = f2b(val);
        }
      }
    }
  }
}

// ---------------- combine: out[t] = w0*(Y[s0]+b2[e0]) + w1*(Y[s1]+b2[e1]) + Y[sh]+bs2 ----
__global__ void combine_kernel(const u16* __restrict__ Ytmp, const int* __restrict__ slot_of,
                               const int* __restrict__ top_e, const float* __restrict__ top_w,
                               const float* __restrict__ b2, const float* __restrict__ bs2,
                               const int* __restrict__ pad_off, float* __restrict__ out) {
  constexpr size_t YHALF = (size_t)MAXRB * 128 * DM;
  int gid = blockIdx.x * blockDim.x + threadIdx.x;   // one per (token, 8-col group)
  int t = gid >> 7;
  int c8 = (gid & 127) * 8;
  if (t >= T_TOK) return;
  int shbase = pad_off[NE];
  int s0 = slot_of[t * 2], s1 = slot_of[t * 2 + 1];
  int e0 = top_e[t * 2],  e1 = top_e[t * 2 + 1];
  float w0 = top_w[t * 2], w1 = top_w[t * 2 + 1];
  u16x8 y0a = *reinterpret_cast<const u16x8*>(Ytmp + (size_t)s0 * DM + c8);
  u16x8 y0b = *reinterpret_cast<const u16x8*>(Ytmp + YHALF + (size_t)s0 * DM + c8);
  u16x8 y1a = *reinterpret_cast<const u16x8*>(Ytmp + (size_t)s1 * DM + c8);
  u16x8 y1b = *reinterpret_cast<const u16x8*>(Ytmp + YHALF + (size_t)s1 * DM + c8);
  u16x8 ysa = *reinterpret_cast<const u16x8*>(Ytmp + (size_t)(shbase + t) * DM + c8);
  u16x8 ysb = *reinterpret_cast<const u16x8*>(Ytmp + YHALF + (size_t)(shbase + t) * DM + c8);
  const float* b0 = b2 + (size_t)e0 * DM + c8;
  const float* b1p = b2 + (size_t)e1 * DM + c8;
  const float* bs = bs2 + c8;
  float r[8];
#pragma unroll
  for (int v = 0; v < 8; ++v)
    r[v] = w0 * (b2f(y0a[v]) + b2f(y0b[v]) + b0[v])
         + w1 * (b2f(y1a[v]) + b2f(y1b[v]) + b1p[v])
         + (b2f(ysa[v]) + b2f(ysb[v]) + bs[v]);
  float* o = out + (size_t)t * DM + c8;
#pragma unroll
  for (int v = 0; v < 8; ++v) o[v] = r[v];
}

extern "C" void kernel_launch(void* const* d_in, const int* in_sizes, int n_in,
                              void* d_out, int out_size, void* d_ws, size_t ws_size,
                              hipStream_t stream) {
  const float* x   = (const float*)d_in[0];
  const float* Wg  = (const float*)d_in[1];
  const float* W1  = (const float*)d_in[2];
  const float* b1  = (const float*)d_in[3];
  const float* W2  = (const float*)d_in[4];
  const float* b2  = (const float*)d_in[5];
  const float* Ws1 = (const float*)d_in[6];
  const float* bs1 = (const float*)d_in[7];
  const float* Ws2 = (const float*)d_in[8];
  const float* bs2 = (const float*)d_in[9];

  // workspace layout (~276 MiB)
  char* ws = (char*)d_ws;
  size_t off = 0;
  auto alloc = [&](size_t bytes) -> char* {
    char* p = ws + off;
    off = (off + bytes + 255) & ~(size_t)255;
    return p;
  };
  int*   pad_off = (int*)  alloc((NE + 2) * 4);
  int*   top_e   = (int*)  alloc((size_t)T_TOK * 2 * 4);
  float* top_w   = (float*)alloc((size_t)T_TOK * 2 * 4);
  int*   slot_of = (int*)  alloc((size_t)T_TOK * 2 * 4);
  u16*   Xb   = (u16*)alloc((size_t)T_TOK * DM * 2);         // 8 MB
  u16*   Xg   = (u16*)alloc((size_t)9216 * DM * 2);          // padded expert rows, 19 MB
  u16*   W1T  = (u16*)alloc((size_t)NE * DM * DF * 2);       // [e][DF][DM], 64 MB; dead after pass1
  u16*   W2T  = (u16*)alloc((size_t)NE * DM * DF * 2);       // [e][DM][DF], 64 MB
  u16*   Ws1T = (u16*)alloc((size_t)DM * DF * 2);            // [DF][DM], 8 MB
  u16*   Ws2T = (u16*)alloc((size_t)DM * DF * 2);            // [DM][DF], 8 MB
  u16*   H    = (u16*)alloc((size_t)MAXRB * 128 * DF * 2);   // 13312 rows, 104 MB
  u16*   Ytmp = W1T;   // 52 MB overlay (2 split-K halves): W1T rewritten every launch
  (void)ws_size; (void)in_sizes; (void)n_in;

  transpose_w<<<2 * 9 * 1024, 256, 0, stream>>>(W1, Ws1, W2, Ws2, W1T, Ws1T, W2T, Ws2T);
  gating_cvt<<<T_TOK / 4, 256, 0, stream>>>(x, Wg, Xb, top_e, top_w);
  slots_kernel<<<1, 256, 0, stream>>>(top_e, pad_off, slot_of);
  gather_x<<<2 * T_TOK, 128, 0, stream>>>(Xb, slot_of, Xg);

  // pass1: 32 colb x 104 rb = 3328 blocks, L2-blocked per XCD
  ffn_gemm<1><<<(DF / 128) * MAXRB, 256, 0, stream>>>(
      Xb, Xg, H, W1T, Ws1T, b1, bs1, pad_off, Ytmp);
  // pass2: 8 colb x 104 rb x 2 ks = 1664 blocks
  ffn_gemm<2><<<(DM / 128) * MAXRB * 2, 256, 0, stream>>>(
      Xb, Xg, H, W2T, Ws2T, b2, bs2, pad_off, Ytmp);

  combine_kernel<<<(T_TOK * 128) / 256, 256, 0, stream>>>(
      Ytmp, slot_of, top_e, top_w, b2, bs2, pad_off, (float*)d_out);
}

// Round 10
// 371.153 us; speedup vs baseline: 1.9705x; 1.0395x over previous
//
#include <hip/hip_runtime.h>
#include <hip/hip_bf16.h>
#include <cstdint>
#include <cstddef>

// Problem constants
#define T_TOK 4096   // BATCH*SEQ
#define DM    1024   // D_MODEL
#define DF    4096   // D_FF
#define NE    8      // N_EXPERTS (TOP_K = 2)
#define MAXRB 104    // 128-row blocks: padded experts (<=72) + shared (32)
#define RBX   13     // row-blocks per XCD (104/8)

typedef unsigned short u16;
typedef __attribute__((ext_vector_type(8))) short  short8;
typedef __attribute__((ext_vector_type(8))) unsigned short u16x8;
typedef __attribute__((ext_vector_type(4))) float  f32x4;
typedef __attribute__((ext_vector_type(4))) unsigned short u16x4;

__device__ __forceinline__ u16 f2b(float f) {
  union { float f; uint32_t u; } v; v.f = f;
  uint32_t u = v.u;
  u += 0x7fffu + ((u >> 16) & 1u);   // round-to-nearest-even
  return (u16)(u >> 16);
}
__device__ __forceinline__ float b2f(u16 b) {
  union { uint32_t u; float f; } v; v.u = ((uint32_t)b) << 16; return v.f;
}

// async global->LDS, 16B per lane. LDS dest is WAVE-UNIFORM base; HW adds lane*16.
__device__ __forceinline__ void gload_lds16(const u16* gsrc, u16* lds) {
  __builtin_amdgcn_global_load_lds(
      (const __attribute__((address_space(1))) void*)gsrc,
      (__attribute__((address_space(3))) void*)lds, 16, 0, 0);
}

// ---------------- transpose+convert, one weight family (9 slices) -------------------
// src fp32 [SRC_R][SRC_C] -> dst bf16 [SRC_C][SRC_R]. f32x4 reads (16B/lane, G13).
// Launched right before its consumer GEMM so the bf16 output is LLC-hot.
template <int SRC_R, int SRC_C>
__global__ void transpose_w(const float* __restrict__ W, const float* __restrict__ Wsh,
                            u16* __restrict__ WT, u16* __restrict__ WsT) {
  __shared__ float tile[64][65];
  const int id = blockIdx.x;
  const int z = id >> 10, t = id & 1023;     // 1024 = (SRC_R/64)*(SRC_C/64)
  const float* src; u16* dst;
  const size_t zoff = (size_t)z * DM * DF;
  if (z < NE) { src = W + zoff; dst = WT + zoff; } else { src = Wsh; dst = WsT; }
  constexpr int NBX = SRC_C / 64;
  const int bx = t % NBX, by = t / NBX;
  const int c0 = bx * 64, r0 = by * 64;
  const int tid = threadIdx.x;               // 256
  const int rx = tid >> 4, c4 = (tid & 15) * 4;
#pragma unroll
  for (int i = 0; i < 64; i += 16) {
    f32x4 v = *reinterpret_cast<const f32x4*>(&src[(size_t)(r0 + rx + i) * SRC_C + c0 + c4]);
    tile[rx + i][c4]     = v.x; tile[rx + i][c4 + 1] = v.y;
    tile[rx + i][c4 + 2] = v.z; tile[rx + i][c4 + 3] = v.w;
  }
  __syncthreads();
  const int p = tid & 7, i0 = tid >> 3;      // 8 lanes x 16B = 128B contiguous per i
#pragma unroll
  for (int i = i0; i < 64; i += 32) {
    u16x8 v;
#pragma unroll
    for (int j = 0; j < 8; ++j) v[j] = f2b(tile[8 * p + j][i]);
    *reinterpret_cast<u16x8*>(&dst[(size_t)(c0 + i) * SRC_R + r0 + 8 * p]) = v;
  }
}

// ---------------- gating + x conversion fused: fp32 logits, top-2, write Xb ----------
__global__ void gating_cvt(const float* __restrict__ x, const float* __restrict__ Wg,
                           u16* __restrict__ Xb, int* __restrict__ top_e,
                           float* __restrict__ top_w) {
  int t = (blockIdx.x * blockDim.x + threadIdx.x) >> 6;
  int lane = threadIdx.x & 63;
  if (t >= T_TOK) return;
  const float* xr = x + (size_t)t * DM;
  u16* xbr = Xb + (size_t)t * DM;
  float acc[NE];
#pragma unroll
  for (int e = 0; e < NE; ++e) acc[e] = 0.f;
#pragma unroll
  for (int it = 0; it < 4; ++it) {
    int d0 = it * 256 + lane * 4;
    f32x4 v = *reinterpret_cast<const f32x4*>(xr + d0);
    u16x4 o;
    o.x = f2b(v.x); o.y = f2b(v.y); o.z = f2b(v.z); o.w = f2b(v.w);
    *reinterpret_cast<u16x4*>(xbr + d0) = o;
#pragma unroll
    for (int j = 0; j < 4; ++j) {
      const float* wr = Wg + (size_t)(d0 + j) * NE;
      float xv = v[j];
#pragma unroll
      for (int e = 0; e < NE; ++e) acc[e] += xv * wr[e];
    }
  }
#pragma unroll
  for (int off = 32; off > 0; off >>= 1) {
#pragma unroll
    for (int e = 0; e < NE; ++e) acc[e] += __shfl_down(acc[e], off);
  }
  if (lane == 0) {
    int e0 = 0; float v0 = acc[0];
#pragma unroll
    for (int e = 1; e < NE; ++e) if (acc[e] > v0) { v0 = acc[e]; e0 = e; }
    int e1 = -1; float v1 = -3.4e38f;
#pragma unroll
    for (int e = 0; e < NE; ++e) if (e != e0 && acc[e] > v1) { v1 = acc[e]; e1 = e; }
    float s = expf(v1 - v0);              // v1 <= v0, stable
    float inv = 1.f / (1.f + s);
    top_e[t * 2] = e0; top_e[t * 2 + 1] = e1;
    top_w[t * 2] = inv; top_w[t * 2 + 1] = s * inv;
  }
}

// ---------------- deterministic slot assignment: 1 block, LDS prefix scan -----------
__global__ void slots_kernel(const int* __restrict__ top_e, int* __restrict__ pad_off,
                             int* __restrict__ slot_of) {
  __shared__ int cnt[256][NE];    // 8 KB
  __shared__ int pos[NE + 2];
  const int tid = threadIdx.x;
  const int p0 = tid * 32;        // 256 threads x 32 pairs = 8192
#pragma unroll
  for (int e = 0; e < NE; ++e) cnt[tid][e] = 0;
#pragma unroll 1
  for (int i = 0; i < 32; ++i) cnt[tid][top_e[p0 + i]]++;
  __syncthreads();
  if (tid < NE) {                 // exclusive scan over threads, per expert
    int s = 0;
    for (int i = 0; i < 256; ++i) { int c = cnt[i][tid]; cnt[i][tid] = s; s += c; }
    pos[tid] = s;                 // total count for expert tid
  }
  __syncthreads();
  if (tid == 0) {
    int s = 0;
    for (int e = 0; e < NE; ++e) { int c = pos[e]; pos[e] = s; s += (c + 127) & ~127; }
    pos[NE] = s;                  // shared-expert base row
    pos[NE + 1] = s + T_TOK;      // total padded rows
  }
  __syncthreads();
#pragma unroll
  for (int e = 0; e < NE; ++e) cnt[tid][e] += pos[e];   // absolute running slot
#pragma unroll 1
  for (int i = 0; i < 32; ++i) {
    int e = top_e[p0 + i];
    slot_of[p0 + i] = cnt[tid][e]++;
  }
  if (tid < NE + 2) pad_off[tid] = pos[tid];
}

// ---------------- gather: copy Xb row to its slot in padded grouped Xg ----------------
__global__ void gather_x(const u16* __restrict__ Xb, const int* __restrict__ slot_of,
                         u16* __restrict__ Xg) {
  int p = blockIdx.x;                 // 0..2*T_TOK-1 ; token = p>>1
  int slot = slot_of[p];
  u16x8 v = reinterpret_cast<const u16x8*>(Xb + (size_t)(p >> 1) * DM)[threadIdx.x];
  reinterpret_cast<u16x8*>(Xg + (size_t)slot * DM)[threadIdx.x] = v;
}

// ---------------- grouped FFN GEMM: m97 structure, 128x128 tile, 4 waves -------------
// Dense padded row-space; 32KB LDS; __launch_bounds__(256,4): 64 VGPR + 64 acc-AGPR
// = 128 regs/wave fits EXACTLY at 4 waves/EU ((256,5) spilled acc: r8, WRITE 698MB).
// PASS 1: H[row] = relu(A[row] @ W1T^T + b1)   A = Xg (experts) / Xb (shared), K=1024
// PASS 2: Ytmp[ks][row] = H[row] @ W2T[ks]^T   K=4096 split 2x2048; bias+gate in combine
// L2-blocked swizzle (verified r9: FETCH 443->150MB): rbs partitioned across XCDs
// (13 each), rb innermost per XCD -> per-XCD A-set (3.3MB) L2-resident.
// LDS linear (gload_lds); conflicts killed by chunk-XOR on BOTH source and ds_read.
template <int PASS>
__global__ __launch_bounds__(256, 4)
void ffn_gemm(const u16* __restrict__ Xb, const u16* __restrict__ Xg,
              u16* __restrict__ H,
              const u16* __restrict__ WT, const u16* __restrict__ WsT,
              const float* __restrict__ bias_e, const float* __restrict__ bias_s,
              const int* __restrict__ pad_off, u16* __restrict__ Ytmp) {
  constexpr int K      = (PASS == 1) ? DM : DF;
  constexpr int N      = (PASS == 1) ? DF : DM;
  constexpr int KSPLIT = (PASS == 1) ? 1 : 2;
  constexpr int KLEN   = K / KSPLIT;
  constexpr size_t YHALF = (size_t)MAXRB * 128 * DM;

  // XCD-partitioned, L2-blocked ordering (blockIdx round-robins XCDs mod 8)
  const int xcd = blockIdx.x & 7;
  const int c   = blockIdx.x >> 3;        // [0, NWG/8)
  const int rb  = xcd * RBX + c % RBX;    // rb innermost: A-set L2-resident per XCD
  const int cq  = c / RBX;
  int colb, ks;
  if (PASS == 1) { colb = cq; ks = 0; }
  else           { ks = cq >> 3; colb = cq & 7; }
  const int col0 = colb * 128;
  const int kbase = ks * KLEN;

  const int shbase = pad_off[NE];
  const int mtot   = pad_off[NE + 1];
  const int grow0  = rb * 128;            // global padded row (tile never spans experts)
  if (grow0 >= mtot) return;

  int e = NE;                             // shared unless below shbase
  if (grow0 < shbase) {
    e = 0;
#pragma unroll
    for (int i = 1; i < NE; ++i) if (grow0 >= pad_off[i]) e = i;
  }

  const u16* Ap;
  if (PASS == 1) Ap = (e < NE) ? (Xg + (size_t)grow0 * DM)
                               : (Xb + (size_t)(grow0 - shbase) * DM);
  else           Ap = H + (size_t)grow0 * DF;
  const u16* Bp = (e < NE) ? (WT + (size_t)e * (size_t)K * N) : WsT;   // [N][K]
  const float* bias = (e < NE) ? (bias_e + (size_t)e * N) : bias_s;

  __shared__ alignas(16) u16 As[128 * 64];
  __shared__ alignas(16) u16 Bs[128 * 64];

  const int tid = threadIdx.x;
  const int wv = tid >> 6, lane = tid & 63;
  // staging: call j covers rows j*32 + (wv*8 + lane>>3); 16B chunk = lane&7 (XOR-swz)
  const int srow = wv * 8 + (lane >> 3);
  const int schk = lane & 7;
  const u16* a_ptr[4];
  const u16* b_ptr[4];
#pragma unroll
  for (int j = 0; j < 4; ++j) {
    int r = j * 32 + srow;
    int cs = (schk ^ (r & 7)) * 8;        // pre-swizzled global column (elems)
    a_ptr[j] = Ap + (size_t)r * K + kbase + cs;
    b_ptr[j] = Bp + (size_t)(col0 + r) * K + kbase + cs;
  }
  const int ldso = wv * 512;              // wave-uniform LDS elem offset per 4KB call

  const int wr = wv >> 1, wc = wv & 1;    // 2x2 wave grid; per-wave output 64x64
  const int q = lane >> 4, r16 = lane & 15, r7 = r16 & 7;
  const int xk0 = (q ^ r7) * 8;           // kk=0: logical chunk q   -> phys
  const int xk1 = ((4 + q) ^ r7) * 8;     // kk=1: logical chunk 4+q -> phys

  f32x4 acc[4][4];
#pragma unroll
  for (int i = 0; i < 4; ++i)
#pragma unroll
    for (int j = 0; j < 4; ++j) acc[i][j] = (f32x4)0.f;

#pragma unroll 1
  for (int k0 = 0; k0 < KLEN; k0 += 64) {
    __syncthreads();                      // prev iter's LDS reads done
#pragma unroll
    for (int j = 0; j < 4; ++j) gload_lds16(a_ptr[j] + k0, As + j * 2048 + ldso);
#pragma unroll
    for (int j = 0; j < 4; ++j) gload_lds16(b_ptr[j] + k0, Bs + j * 2048 + ldso);
    __syncthreads();                      // vmcnt(0) drain at barrier: tile ready
#pragma unroll
    for (int kk = 0; kk < 2; ++kk) {
      const int xk = kk ? xk1 : xk0;
      short8 af[4], bf[4];
#pragma unroll
      for (int mt = 0; mt < 4; ++mt)
        af[mt] = *reinterpret_cast<const short8*>(&As[(wr * 64 + mt * 16 + r16) * 64 + xk]);
#pragma unroll
      for (int nt = 0; nt < 4; ++nt)
        bf[nt] = *reinterpret_cast<const short8*>(&Bs[(wc * 64 + nt * 16 + r16) * 64 + xk]);
#pragma unroll
      for (int mt = 0; mt < 4; ++mt)
#pragma unroll
        for (int nt = 0; nt < 4; ++nt)
          acc[mt][nt] = __builtin_amdgcn_mfma_f32_16x16x32_bf16(af[mt], bf[nt], acc[mt][nt], 0, 0, 0);
    }
  }

  // epilogue: C/D layout col=lane&15, row=(lane>>4)*4+reg  [verified m89/m91]
  u16* Yt = Ytmp + (size_t)ks * YHALF;
#pragma unroll
  for (int mt = 0; mt < 4; ++mt) {
    int rl = wr * 64 + mt * 16 + q * 4;
#pragma unroll
    for (int nt = 0; nt < 4; ++nt) {
      int col = col0 + wc * 64 + nt * 16 + r16;
      float bcol = (PASS == 1) ? bias[col] : 0.f;
#pragma unroll
      for (int v = 0; v < 4; ++v) {
        int r = rl + v;
        float val = acc[mt][nt][v] + bcol;
        if (PASS == 1) {
          val = fmaxf(val, 0.f);
          H[(size_t)(grow0 + r) * DF + col] = f2b(val);
        } else {
          Yt[(size_t)(grow0 + r) * DM + col] = f2b(val);
        }
      }
    }
  }
}

// ---------------- combine: out[t] = w0*(Y[s0]+b2[e0]) + w1*(Y[s1]+b2[e1]) + Y[sh]+bs2 ----
__global__ void combine_kernel(const u16* __restrict__ Ytmp, const int* __restrict__ slot_of,
                               const int* __restrict__ top_e, const float* __restrict__ top_w,
                               const float* __restrict__ b2, const float* __restrict__ bs2,
                               const int* __restrict__ pad_off, float* __restrict__ out) {
  constexpr size_t YHALF = (size_t)MAXRB * 128 * DM;
  int gid = blockIdx.x * blockDim.x + threadIdx.x;   // one per (token, 8-col group)
  int t = gid >> 7;
  int c8 = (gid & 127) * 8;
  if (t >= T_TOK) return;
  int shbase = pad_off[NE];
  int s0 = slot_of[t * 2], s1 = slot_of[t * 2 + 1];
  int e0 = top_e[t * 2],  e1 = top_e[t * 2 + 1];
  float w0 = top_w[t * 2], w1 = top_w[t * 2 + 1];
  u16x8 y0a = *reinterpret_cast<const u16x8*>(Ytmp + (size_t)s0 * DM + c8);
  u16x8 y0b = *reinterpret_cast<const u16x8*>(Ytmp + YHALF + (size_t)s0 * DM + c8);
  u16x8 y1a = *reinterpret_cast<const u16x8*>(Ytmp + (size_t)s1 * DM + c8);
  u16x8 y1b = *reinterpret_cast<const u16x8*>(Ytmp + YHALF + (size_t)s1 * DM + c8);
  u16x8 ysa = *reinterpret_cast<const u16x8*>(Ytmp + (size_t)(shbase + t) * DM + c8);
  u16x8 ysb = *reinterpret_cast<const u16x8*>(Ytmp + YHALF + (size_t)(shbase + t) * DM + c8);
  const float* b0 = b2 + (size_t)e0 * DM + c8;
  const float* b1p = b2 + (size_t)e1 * DM + c8;
  const float* bs = bs2 + c8;
  float r[8];
#pragma unroll
  for (int v = 0; v < 8; ++v)
    r[v] = w0 * (b2f(y0a[v]) + b2f(y0b[v]) + b0[v])
         + w1 * (b2f(y1a[v]) + b2f(y1b[v]) + b1p[v])
         + (b2f(ysa[v]) + b2f(ysb[v]) + bs[v]);
  float* o = out + (size_t)t * DM + c8;
#pragma unroll
  for (int v = 0; v < 8; ++v) o[v] = r[v];
}

extern "C" void kernel_launch(void* const* d_in, const int* in_sizes, int n_in,
                              void* d_out, int out_size, void* d_ws, size_t ws_size,
                              hipStream_t stream) {
  const float* x   = (const float*)d_in[0];
  const float* Wg  = (const float*)d_in[1];
  const float* W1  = (const float*)d_in[2];
  const float* b1  = (const float*)d_in[3];
  const float* W2  = (const float*)d_in[4];
  const float* b2  = (const float*)d_in[5];
  const float* Ws1 = (const float*)d_in[6];
  const float* bs1 = (const float*)d_in[7];
  const float* Ws2 = (const float*)d_in[8];
  const float* bs2 = (const float*)d_in[9];

  // workspace layout (~276 MiB)
  char* ws = (char*)d_ws;
  size_t off = 0;
  auto alloc = [&](size_t bytes) -> char* {
    char* p = ws + off;
    off = (off + bytes + 255) & ~(size_t)255;
    return p;
  };
  int*   pad_off = (int*)  alloc((NE + 2) * 4);
  int*   top_e   = (int*)  alloc((size_t)T_TOK * 2 * 4);
  float* top_w   = (float*)alloc((size_t)T_TOK * 2 * 4);
  int*   slot_of = (int*)  alloc((size_t)T_TOK * 2 * 4);
  u16*   Xb   = (u16*)alloc((size_t)T_TOK * DM * 2);         // 8 MB
  u16*   Xg   = (u16*)alloc((size_t)9216 * DM * 2);          // padded expert rows, 19 MB
  u16*   W1T  = (u16*)alloc((size_t)NE * DM * DF * 2);       // [e][DF][DM], 64 MB; dead after pass1
  u16*   W2T  = (u16*)alloc((size_t)NE * DM * DF * 2);       // [e][DM][DF], 64 MB
  u16*   Ws1T = (u16*)alloc((size_t)DM * DF * 2);            // [DF][DM], 8 MB
  u16*   Ws2T = (u16*)alloc((size_t)DM * DF * 2);            // [DM][DF], 8 MB
  u16*   H    = (u16*)alloc((size_t)MAXRB * 128 * DF * 2);   // 13312 rows, 104 MB
  u16*   Ytmp = W1T;   // 52 MB overlay (2 split-K halves): W1T rewritten every launch
  (void)ws_size; (void)in_sizes; (void)n_in;

  // prologue first; each transpose lands right before its consumer GEMM (LLC-hot)
  gating_cvt<<<T_TOK / 4, 256, 0, stream>>>(x, Wg, Xb, top_e, top_w);
  slots_kernel<<<1, 256, 0, stream>>>(top_e, pad_off, slot_of);
  gather_x<<<2 * T_TOK, 128, 0, stream>>>(Xb, slot_of, Xg);

  transpose_w<DM, DF><<<9 * 1024, 256, 0, stream>>>(W1, Ws1, W1T, Ws1T);
  // pass1: 32 colb x 104 rb = 3328 blocks, L2-blocked per XCD
  ffn_gemm<1><<<(DF / 128) * MAXRB, 256, 0, stream>>>(
      Xb, Xg, H, W1T, Ws1T, b1, bs1, pad_off, Ytmp);

  transpose_w<DF, DM><<<9 * 1024, 256, 0, stream>>>(W2, Ws2, W2T, Ws2T);
  // pass2: 8 colb x 104 rb x 2 ks = 1664 blocks
  ffn_gemm<2><<<(DM / 128) * MAXRB * 2, 256, 0, stream>>>(
      Xb, Xg, H, W2T, Ws2T, b2, bs2, pad_off, Ytmp);

  combine_kernel<<<(T_TOK * 128) / 256, 256, 0, stream>>>(
      Ytmp, slot_of, top_e, top_w, b2, bs2, pad_off, (float*)d_out);
}